// Round 7
// baseline (105.434 us; speedup 1.0000x reference)
//
#include <hip/hip_runtime.h>
#include <math.h>

// StructureLoss — R14: R13 structure + register reuse + raw-t LDS relay.
// R13 (100.5, best): 512 blocks (2/CU) x 512 thr, 32-row bands, vls-only LDS.
// Remaining waste, by inspection: (1) the 32 tail-row loads/block duplicate
// warm[]/hd0[] registers; (2) stage-2 re-reads 16 center t-rows from GLOBAL
// (64KB/block) though every value transits phase-1 registers. R14: tails from
// registers (94->62 row-loads/block = exactly unique coverage) and a second
// skewed LDS tile traw[] written during the march (compile-time register
// select), so stage 2 reads t from LDS. Stage-2 global loads: x only.
// LDS 74.9KB -> still 2 blocks/CU. Same arithmetic order everywhere
// (values are bitwise copies) -> absmax 0 preserved.

#define IMG_H 512
#define IMG_W 512
#define NB    32
#define HW    (IMG_H * IMG_W)
#define BANDS 16              // 32-row bands per image
#define NBLK  (NB * BANDS)    // 512 blocks -> 2 per CU
#define NTH   512
#define VST   584             // LDS row stride (floats), skewed layout

__device__ __forceinline__ float wave_reduce(float v) {
#pragma unroll
  for (int off = 32; off > 0; off >>= 1) v += __shfl_down(v, off, 64);
  return v;
}

// stage2 for 16 rows in vls/traw; consumes XGv register x-tile
#define STAGE2(XGv)                                                            \
  {                                                                            \
    const float* vb = &vls[row * VST + cb];                                    \
    float q16[16];                                                             \
    {                                                                          \
      float run = 0.f;                                                         \
      _Pragma("unroll")                                                        \
      for (int e = 0; e < 4; ++e) {                                            \
        float4 vv = *(const float4*)(vb + 4 * e);                              \
        q16[4 * e + 0] = run + vv.x;                                           \
        q16[4 * e + 1] = q16[4 * e + 0] + vv.y;                                \
        q16[4 * e + 2] = q16[4 * e + 1] + vv.z;                                \
        q16[4 * e + 3] = q16[4 * e + 2] + vv.w;                                \
        run = q16[4 * e + 3];                                                  \
      }                                                                        \
    }                                                                          \
    {                                                                          \
      float tot = q16[15], ss = tot;                                           \
      _Pragma("unroll")                                                        \
      for (int d = 1; d < 32; d <<= 1) {                                       \
        float uu = __shfl_up(ss, d, 64);                                       \
        if (sub >= d) ss += uu;                                                \
      }                                                                        \
      float pb = ss - tot;                                                     \
      _Pragma("unroll")                                                        \
      for (int j = 0; j < 16; ++j) q16[j] += pb;   /* q16[j] = P[16*sub+j] */  \
    }                                                                          \
    float4 tq[4];                                                              \
    const float* tb2 = &traw[row * VST + cb];                                  \
    _Pragma("unroll")                                                          \
    for (int e = 0; e < 4; ++e) tq[e] = *(const float4*)(tb2 + 4 * e);         \
    _Pragma("unroll")                                                          \
    for (int e = 0; e < 4; ++e) {                                              \
      float xa[4] = {XGv[e].x, XGv[e].y, XGv[e].z, XGv[e].w};                  \
      float ta[4] = {tq[e].x, tq[e].y, tq[e].z, tq[e].w};                      \
      _Pragma("unroll")                                                        \
      for (int l = 0; l < 4; ++l) {                                            \
        const int j = 4 * e + l;                                               \
        float hi;                                                              \
        if (j == 0) {                                                          \
          hi = q16[15];                                                        \
        } else {                                                               \
          float gd = __shfl_down(q16[j - 1], 1, 64);                           \
          hi = (sub == 31) ? q16[15] : gd;         /* P[min(c+15,511)] */      \
        }                                                                      \
        float gu = __shfl_up(q16[j], 1, 64);                                   \
        float lo = (sub == 0) ? 0.f : gu;          /* P[c-16] or 0 */          \
        float box = hi - lo;                                                   \
        float tv = ta[l], xv = xa[l];                                          \
        float w   = fmaf(5.0f, fabsf(box * inv_area - tv), 1.0f);              \
        float ez  = __expf(-fabsf(xv));                                        \
        float iv  = 1.0f / (1.0f + ez);                                        \
        float p   = (xv >= 0.f) ? iv : ez * iv;    /* sigmoid(x) */            \
        float bce = fmaxf(xv, 0.f) - xv * tv + __logf(1.0f + ez);              \
        aW  += w;                                                              \
        aWB = fmaf(w, bce, aWB);                                               \
        aI  = fmaf(p * tv, w, aI);                                             \
        aU  = fmaf(p + tv, w, aU);                                             \
      }                                                                        \
    }                                                                          \
  }

// 512 blocks: xcd(8) x k(64); 4 images per XCD, 16 bands per image.
__global__ __launch_bounds__(NTH, 4) void sloss_main(const float* __restrict__ x,
                                                     const float* __restrict__ t,
                                                     float* __restrict__ part) {
  __shared__ __align__(16) float vls[16 * VST];    // 37,376 B vertical sums
  __shared__ __align__(16) float traw[16 * VST];   // 37,376 B raw-t relay
  __shared__ float red[8][4];

  const int tid  = threadIdx.x;
  const int bid  = blockIdx.x;
  const int xcd  = bid & 7;
  const int k    = bid >> 3;               // 0..63
  const int img  = (xcd << 2) | (k >> 4);  // 4 images per XCD
  const int band = k & 15;                 // 16 bands per image
  const int r0   = band * 32;
  const float* tb = t + (size_t)img * HW;
  const float* xb = x + (size_t)img * HW;
  const float* tc = tb + tid;              // phase-1: thread = column tid

  const int li  = tid + 4 * (tid >> 5);    // skewed col index for LDS writes
  const int row = tid >> 5;                // stage-2 row 0..15
  const int sub = tid & 31;                // stage-2 16-col chunk 0..31
  const int cb  = 36 * (sub >> 1) + 16 * (sub & 1);
  const float inv_area = 1.0f / 961.0f;

  // ---- phase-1 loads: 62 unique rows only (warm 30 + hd0 16 + hd1 16) ----
  float warm[30];
#pragma unroll
  for (int j = 0; j < 30; ++j) {
    int r = r0 - 15 + j;
    warm[j] = ((unsigned)r < IMG_H) ? tc[(size_t)r * IMG_W] : 0.f;
  }
  float hd0[16];
#pragma unroll
  for (int i = 0; i < 16; ++i) {
    int r = r0 + 15 + i;
    hd0[i] = ((unsigned)r < IMG_H) ? tc[(size_t)r * IMG_W] : 0.f;
  }
  float4 xg0[4];
  const size_t base0 = (size_t)(r0 + row) * IMG_W + 16 * sub;
#pragma unroll
  for (int e = 0; e < 4; ++e) xg0[e] = *(const float4*)(xb + base0 + 4 * e);

  // warm-up sum (sequential, same order as R13)
  float sum = 0.f;
#pragma unroll
  for (int j = 0; j < 30; ++j) sum += warm[j];

  float aW = 0.f, aWB = 0.f, aI = 0.f, aU = 0.f;

  // ---- march 0: rows r0..r0+15; tails + center t from registers ----
#pragma unroll
  for (int i = 0; i < 16; ++i) {
    sum += hd0[i];
    vls[i * VST + li]  = sum;
    traw[i * VST + li] = (i < 15) ? warm[15 + i] : hd0[0];  // t[r0+i]
    sum -= warm[i];                                          // t[r0+i-15]
  }
  __syncthreads();

  // issue hd1 (rows r0+31..r0+46); flies under stage-2 #0
  float hd1[16];
#pragma unroll
  for (int i = 0; i < 16; ++i) {
    int r = r0 + 31 + i;
    hd1[i] = ((unsigned)r < IMG_H) ? tc[(size_t)r * IMG_W] : 0.f;
  }

  STAGE2(xg0)
  __syncthreads();

  // ---- march 1: rows r0+16..r0+31 ----
  float4 xg1[4];
  const size_t base1 = base0 + (size_t)16 * IMG_W;
#pragma unroll
  for (int e = 0; e < 4; ++e) xg1[e] = *(const float4*)(xb + base1 + 4 * e);
#pragma unroll
  for (int i = 0; i < 16; ++i) {
    sum += hd1[i];
    vls[i * VST + li]  = sum;
    traw[i * VST + li] = (i < 15) ? hd0[i + 1] : hd1[0];     // t[r0+16+i]
    sum -= (i < 14) ? warm[16 + i] : hd0[i - 14];            // t[r0+1+i]
  }
  __syncthreads();

  STAGE2(xg1)

  // ---- block reduction ----
  aW  = wave_reduce(aW);
  aWB = wave_reduce(aWB);
  aI  = wave_reduce(aI);
  aU  = wave_reduce(aU);
  const int wv = tid >> 6, ln = tid & 63;
  if (ln == 0) { red[wv][0] = aW; red[wv][1] = aWB; red[wv][2] = aI; red[wv][3] = aU; }
  __syncthreads();
  if (tid < 4) {
    float v = 0.f;
#pragma unroll
    for (int w8 = 0; w8 < 8; ++w8) v += red[w8][tid];
    part[(img * BANDS + band) * 4 + tid] = v;
  }
}

// ---- finalize: reduce 512 block-partials -> scalar loss ----
__global__ void sloss_final(const float* __restrict__ part,
                            float* __restrict__ out) {
  __shared__ float s[128];
  int tid = threadIdx.x;          // 128 threads
  int img = tid >> 2, q = tid & 3;
  float v = 0.f;
#pragma unroll 4
  for (int g = 0; g < BANDS; ++g) v += part[((img << 4) + g) * 4 + q];
  s[tid] = v;
  __syncthreads();
  float loss = 0.f;
  if (tid < NB) {
    float aW  = s[tid * 4 + 0];
    float aWB = s[tid * 4 + 1];
    float aI  = s[tid * 4 + 2];
    float aU  = s[tid * 4 + 3];
    loss = aWB / aW + 1.0f - (aI + 1.0f) / (aU - aI + 1.0f);
  }
  loss = wave_reduce(loss);
  if (tid == 0) out[0] = loss * (1.0f / (float)NB);
}

extern "C" void kernel_launch(void* const* d_in, const int* in_sizes, int n_in,
                              void* d_out, int out_size, void* d_ws, size_t ws_size,
                              hipStream_t stream) {
  const float* x = (const float*)d_in[0];
  const float* t = (const float*)d_in[1];
  float* part = (float*)d_ws;     // 512 x 4 floats, fully overwritten

  sloss_main<<<NBLK, NTH, 0, stream>>>(x, t, part);
  sloss_final<<<1, 128, 0, stream>>>(part, (float*)d_out);
}